// Round 4
// baseline (288.123 us; speedup 1.0000x reference)
//
#include <hip/hip_runtime.h>
#include <float.h>

#define LSEQ 1024
#define NCH  8192   // B*H*d = 16*8*64
#define TOPK 13     // int(2*ln(1024))

typedef short bf16x8 __attribute__((ext_vector_type(8)));   // 8 bf16 = 4 VGPRs (MFMA A/B frag)
typedef float f32x16 __attribute__((ext_vector_type(16)));  // MFMA C/D frag

// Per-channel LDS layout (bytes):
//   khi [0,2048)  klo [2048,4096)            (swizzled, circular mod-2048B)
//   qe  [4096, 8256)   1040 dw, interleaved: qe[2d]=hi-pair d, qe[2d+1]=lo-pair d
//   qo  [8256, 12416)  1040 dw, odd-shifted copy, same interleave
#define CH_BYTES 12416

// A-read swizzle: b4 ^= b7, b5 ^= b8 ^ b6.  Spreads the 64 lanes' b128 reads
// (addr = 64*row + 32*ks + 16*H mod 2048) over all 8 bank positions.
// Preserves bits 0..3, so swzA(x+low) = swzA(x)+low for low<16.
__device__ __forceinline__ unsigned swzA(unsigned a) {
  return a ^ ((a >> 3) & 48u) ^ ((a >> 1) & 32u);
}
// residual after bf16 truncation (exact in f32)
__device__ __forceinline__ float resid(float x) {
  return x - __uint_as_float(__float_as_uint(x) & 0xffff0000u);
}
__device__ __forceinline__ f32x16 mfma_bf16(bf16x8 a, bf16x8 b, f32x16 c) {
  return __builtin_amdgcn_mfma_f32_32x32x16_bf16(a, b, c, 0, 0, 0);
}

// ---- Tiled transpose: in[b][r][c] -> out[b][c][r] (still used for V) ------
__global__ __launch_bounds__(256) void transpose_rc(const float* __restrict__ in,
                                                    float* __restrict__ out,
                                                    int rows, int cols) {
  __shared__ float tile[32][33];
  int b  = blockIdx.z;
  int r0 = blockIdx.y * 32, c0 = blockIdx.x * 32;
  const float* src = in  + (size_t)b * rows * cols;
  float*       dst = out + (size_t)b * rows * cols;
  int tx = threadIdx.x, ty = threadIdx.y;   // block (32,8)
#pragma unroll
  for (int j = 0; j < 32; j += 8)
    tile[ty + j][tx] = src[(size_t)(r0 + ty + j) * cols + (c0 + tx)];
  __syncthreads();
#pragma unroll
  for (int j = 0; j < 32; j += 8)
    dst[(size_t)(c0 + ty + j) * rows + (r0 + tx)] = tile[tx][ty + j];
}

// ---- MFMA circular correlation + top-13 + softmax -------------------------
// One wave per channel; block stages its 4 channels cooperatively DIRECTLY
// from raw Q,K [B,1024,512] (each float4 covers exactly the block's 4
// channels), writing packed bf16 hi/lo via ds_write_b16 into the identical
// byte layout the round-2 kernel used (validated).  Main loop per K-step:
// 2 swizzled b128 (k hi/lo) + 4 aligned b64 (interleaved q hi/lo) + 3 MFMA.
//   D[a][v] = sum_t k[(t+32a) mod 1024] * q[(t - r'(v)) mod 1024]
//           = corr'[32a + r'(v)],   r'(v) = 2*(v&15) + (v>>4)
// tau = (1024 - tau') & 1023.
__global__ __launch_bounds__(256) void corr_topk_kernel(const float* __restrict__ Qg,
                                                        const float* __restrict__ Kg,
                                                        float* __restrict__ wout,
                                                        int* __restrict__ iout) {
  __shared__ __align__(16) unsigned char lds_raw[4 * CH_BYTES];  // 49664 B
  const int tid = threadIdx.x, wave = tid >> 6, lane = tid & 63;
  const int c0 = blockIdx.x * 4;          // first channel of block
  const int b  = c0 >> 9, col0 = c0 & 511;
  const int c  = c0 + wave;               // this wave's channel

  // ---- block-cooperative staging from raw [B,1024,512] --------------------
  {
    const float* Qb = Qg + ((size_t)b * 1024) * 512 + col0;
    const float* Kb = Kg + ((size_t)b * 1024) * 512 + col0;
#pragma unroll
    for (int j = 0; j < 4; ++j) {
      int t = tid + 256 * j;
      float4 kv = *(const float4*)(Kb + (size_t)t * 512);
      float4 qv = *(const float4*)(Qb + (size_t)t * 512);
      unsigned ka0 = swzA(4u * (unsigned)(t >> 1) + 2u * (unsigned)(t & 1));
      unsigned qa0 = 8u * (unsigned)(t >> 1) + 2u * (unsigned)(t & 1);
      float karr[4] = {kv.x, kv.y, kv.z, kv.w};
      float qarr[4] = {qv.x, qv.y, qv.z, qv.w};
#pragma unroll
      for (int cc = 0; cc < 4; ++cc) {
        unsigned char* ck = lds_raw + cc * CH_BYTES;
        unsigned khiv = __float_as_uint(karr[cc]) >> 16;
        unsigned klov = __float_as_uint(resid(karr[cc])) >> 16;
        *(unsigned short*)(ck + ka0)        = (unsigned short)khiv;
        *(unsigned short*)(ck + 2048 + ka0) = (unsigned short)klov;
        unsigned qhiv = __float_as_uint(qarr[cc]) >> 16;
        unsigned qlov = __float_as_uint(resid(qarr[cc])) >> 16;
        *(unsigned short*)(ck + 4096 + qa0)     = (unsigned short)qhiv;
        *(unsigned short*)(ck + 4096 + qa0 + 4) = (unsigned short)qlov;
        if (t < 8) {  // qe wrap pad: elems 1024..1031 = elems 0..7
          *(unsigned short*)(ck + 8192 + qa0)     = (unsigned short)qhiv;
          *(unsigned short*)(ck + 8192 + qa0 + 4) = (unsigned short)qlov;
        }
      }
    }
  }
  __syncthreads();

  unsigned char* myc = lds_raw + wave * CH_BYTES;

  // ---- build odd-shifted q copy (own channel, own wave) -------------------
  {
    unsigned* qe = (unsigned*)(myc + 4096);
    unsigned* qo = (unsigned*)(myc + 8256);
    uint4 r0 = *(const uint4*)(qe + 16 * lane);
    uint4 r1 = *(const uint4*)(qe + 16 * lane + 4);
    uint4 r2 = *(const uint4*)(qe + 16 * lane + 8);
    uint4 r3 = *(const uint4*)(qe + 16 * lane + 12);
    uint2 r4 = *(const uint2*)(qe + 16 * lane + 16);
    unsigned h9[9] = {r0.x, r0.z, r1.x, r1.z, r2.x, r2.z, r3.x, r3.z, r4.x};
    unsigned l9[9] = {r0.y, r0.w, r1.y, r1.w, r2.y, r2.w, r3.y, r3.w, r4.y};
    unsigned o16[16];
#pragma unroll
    for (int i = 0; i < 8; ++i) {
      o16[2 * i]     = __builtin_amdgcn_alignbyte(h9[i + 1], h9[i], 2);
      o16[2 * i + 1] = __builtin_amdgcn_alignbyte(l9[i + 1], l9[i], 2);
    }
    *(uint4*)(qo + 16 * lane)      = make_uint4(o16[0],  o16[1],  o16[2],  o16[3]);
    *(uint4*)(qo + 16 * lane + 4)  = make_uint4(o16[4],  o16[5],  o16[6],  o16[7]);
    *(uint4*)(qo + 16 * lane + 8)  = make_uint4(o16[8],  o16[9],  o16[10], o16[11]);
    *(uint4*)(qo + 16 * lane + 12) = make_uint4(o16[12], o16[13], o16[14], o16[15]);
    if (lane == 0) {  // qo wrap pad
      *(uint4*)(qo + 1024) = make_uint4(o16[0], o16[1], o16[2], o16[3]);
      *(uint4*)(qo + 1028) = make_uint4(o16[4], o16[5], o16[6], o16[7]);
    }
  }

  // ---- main GEMM loop -----------------------------------------------------
  const int row = lane & 31, Hh = lane >> 5;
  const int rp  = 2 * (row & 15) + (row >> 4);       // fine shift r'(col)
  unsigned e0   = (unsigned)((8 * Hh - rp) & 1023);  // first q element needed
  const int par = rp & 1;
  const unsigned char* bArr = myc + (par ? 8256 : 4096);
  unsigned boff = (((par ? (e0 - 1) : e0) >> 1) * 8u);  // byte offset of pair
  unsigned tb   = (unsigned)(64 * row + 16 * Hh);       // k byte offset (mod 2048)

  f32x16 d = {};
#pragma unroll 4
  for (int ks = 0; ks < 64; ++ks) {
    unsigned sa = swzA(tb);
    uint4 Ah = *(const uint4*)(myc + sa);          // khi b128
    uint4 Al = *(const uint4*)(myc + 2048 + sa);   // klo b128
    uint2 p0 = *(const uint2*)(bArr + boff);
    uint2 p1 = *(const uint2*)(bArr + boff + 8);
    uint2 p2 = *(const uint2*)(bArr + boff + 16);
    uint2 p3 = *(const uint2*)(bArr + boff + 24);
    bf16x8 fah = __builtin_bit_cast(bf16x8, Ah);
    bf16x8 fal = __builtin_bit_cast(bf16x8, Al);
    bf16x8 fbh = __builtin_bit_cast(bf16x8, make_uint4(p0.x, p1.x, p2.x, p3.x));
    bf16x8 fbl = __builtin_bit_cast(bf16x8, make_uint4(p0.y, p1.y, p2.y, p3.y));
    d = mfma_bf16(fah, fbh, d);   // hi*hi
    d = mfma_bf16(fal, fbh, d);   // lo(k)*hi(q)
    d = mfma_bf16(fah, fbl, d);   // hi(k)*lo(q)
    tb   = (tb + 32u) & 2047u;
    boff = (boff + 64u) & 4095u;
  }

  // ---- top-13 straight on the accumulator (tau'-space indices) ------------
  float acc[16];
#pragma unroll
  for (int i = 0; i < 16; ++i) acc[i] = d[i];
  const int ibase = 128 * Hh + rp;

  float topv[TOPK]; int topi[TOPK];
  for (int r = 0; r < TOPK; ++r) {
    float m = -FLT_MAX; int mi = 0x7fffffff;
#pragma unroll
    for (int j = 0; j < 16; ++j) {
      int idx = ibase + 32 * ((j & 3) + 8 * (j >> 2));
      if (acc[j] > m || (acc[j] == m && idx < mi)) { m = acc[j]; mi = idx; }
    }
#pragma unroll
    for (int offx = 32; offx >= 1; offx >>= 1) {
      float om = __shfl_xor(m, offx);
      int   oi = __shfl_xor(mi, offx);
      if (om > m || (om == m && oi < mi)) { m = om; mi = oi; }
    }
    topv[r] = m; topi[r] = mi;
#pragma unroll
    for (int j = 0; j < 16; ++j)        // static-indexed knockout
      acc[j] = (ibase + 32 * ((j & 3) + 8 * (j >> 2)) == mi) ? -FLT_MAX : acc[j];
  }
  float mx = topv[0];
  float wv[TOPK]; float wsum = 0.f;
#pragma unroll
  for (int r = 0; r < TOPK; ++r) { wv[r] = __expf(topv[r] - mx); wsum += wv[r]; }
  float inv = 1.0f / wsum;
  if (lane == 0) {
#pragma unroll
    for (int r = 0; r < TOPK; ++r) {
      wout[(size_t)c * 16 + r] = wv[r] * inv;
      iout[(size_t)c * 16 + r] = (1024 - topi[r]) & 1023;  // tau' -> tau
    }
  }
}

// ---- Fused aggregation + output transpose ---------------------------------
// Block = (b, 16-channel tile, 64-t tile).  Stages 13 clamped windows per
// channel from vT (coalesced), computes out[t][ch] = sum_i w_i * win_i[t],
// transposes through padded LDS, writes out[b][t][c] directly (64B rows).
// tt is the innermost grid dim so consecutive blocks share vT lines in L2/L3.
__global__ __launch_bounds__(256) void agg2_kernel(const float* __restrict__ vT,
                                                   const float* __restrict__ wbuf,
                                                   const int* __restrict__ ibuf,
                                                   float* __restrict__ out) {
  __shared__ float vwin[16][13][64];   // 53248 B
  __shared__ float ws[16][13];
  __shared__ int   is[16][13];
  __shared__ float otile[16][65];      // [ch][t], pad 65 breaks conflicts
  const int tid = threadIdx.x, wave = tid >> 6, lane = tid & 63;
  const int blk = blockIdx.x;
  const int tt = blk & 15, g = blk >> 4;   // g = b*32 + ct
  const int b = g >> 5, ct = g & 31;
  const int c0 = b * 512 + ct * 16;        // first global channel
  const int ch0 = ct * 16;                 // column within d_model
  const int t0 = tt * 64;

  {
    int chn = tid >> 4, ii = tid & 15;
    if (ii < 13) {
      ws[chn][ii] = wbuf[(size_t)(c0 + chn) * 16 + ii];
      is[chn][ii] = ibuf[(size_t)(c0 + chn) * 16 + ii];
    }
  }
  __syncthreads();

  // stage 208 windows, 52 per wave, software-pipelined 8-deep
  for (int m0 = 0; m0 < 52; m0 += 8) {
    float vals[8];
#pragma unroll
    for (int m = 0; m < 8; ++m) {
      if (m0 + m < 52) {
        int u = wave + 4 * (m0 + m);
        int chn = u & 15, i = u >> 4;
        int src = is[chn][i] + t0 + lane;
        src = src < 1023 ? src : 1023;
        vals[m] = vT[(size_t)(c0 + chn) * LSEQ + src];
      }
    }
#pragma unroll
    for (int m = 0; m < 8; ++m) {
      if (m0 + m < 52) {
        int u = wave + 4 * (m0 + m);
        vwin[u & 15][u >> 4][lane] = vals[m];
      }
    }
  }
  __syncthreads();

  // compute: thread (t = lane, wave) handles channels wave, wave+4, +8, +12
#pragma unroll
  for (int s = 0; s < 4; ++s) {
    int chn = wave + 4 * s;
    float a = 0.f;
#pragma unroll
    for (int i = 0; i < TOPK; ++i) a += ws[chn][i] * vwin[chn][i][lane];
    otile[chn][lane] = a;
  }
  __syncthreads();

  // write: thread -> (row r, quad p): out[b][t0+r][ch0 + 4p .. +3]
  {
    int r = tid >> 2, p = tid & 3;
    float o0 = otile[4 * p + 0][r];
    float o1 = otile[4 * p + 1][r];
    float o2 = otile[4 * p + 2][r];
    float o3 = otile[4 * p + 3][r];
    *(float4*)(out + ((size_t)(b * 1024 + t0 + r)) * 512 + ch0 + 4 * p) =
        make_float4(o0, o1, o2, o3);
  }
}

extern "C" void kernel_launch(void* const* d_in, const int* in_sizes, int n_in,
                              void* d_out, int out_size, void* d_ws, size_t ws_size,
                              hipStream_t stream) {
  const float* Q = (const float*)d_in[0];
  const float* K = (const float*)d_in[1];
  const float* V = (const float*)d_in[2];
  float* out = (float*)d_out;
  float* ws  = (float*)d_ws;
  // ws layout (floats): bufA[8192*1024] | ... | w[8192*16] | idx[8192*16]
  float* bufA = ws;
  float* wbuf = ws + (size_t)2 * NCH * LSEQ;
  int*   ibuf = (int*)(wbuf + (size_t)NCH * 16);

  dim3 tb(32, 8);
  corr_topk_kernel<<<NCH / 4, 256, 0, stream>>>(Q, K, wbuf, ibuf);
  transpose_rc<<<dim3(16, 32, 16), tb, 0, stream>>>(V, bufA, 1024, 512);  // vT
  agg2_kernel<<<NCH, 256, 0, stream>>>(bufA, wbuf, ibuf, out);
}

// Round 5
// 246.836 us; speedup vs baseline: 1.1673x; 1.1673x over previous
//
#include <hip/hip_runtime.h>
#include <float.h>

#define LSEQ 1024
#define NCH  8192   // B*H*d = 16*8*64
#define TOPK 13     // int(2*ln(1024))

typedef short bf16x8 __attribute__((ext_vector_type(8)));   // 8 bf16 = 4 VGPRs (MFMA A/B frag)
typedef float f32x16 __attribute__((ext_vector_type(16)));  // MFMA C/D frag

// Per-channel LDS layout (bytes) in the fused kernel:
//   khi [0,2048)  klo [2048,4096)     (swizzled, circular mod-2048B) -- later reused as v row
//   qe  [4096, 8256)  interleaved: byte 8d = hi-pair d, 8d+4 = lo-pair d; pads pairs 512..515
//   qo  [8256, 12416) odd-shifted copy -- later reused as obuf
#define CH_BYTES 12416

// A-read swizzle: b4 ^= b7, b5 ^= b8 ^ b6.  Spreads the 64 lanes' b128 reads
// (addr = 64*row + 32*ks + 16*H mod 2048) over all 8 bank positions.
// Only bits 4,5 change -> swzA(a+x) = swzA(a)+x within a 16B block.
__device__ __forceinline__ unsigned swzA(unsigned a) {
  return a ^ ((a >> 3) & 48u) ^ ((a >> 1) & 32u);
}
// pack bf16(hi16) of two f32 into one word: low half = lo-arg, high half = hi-arg
__device__ __forceinline__ unsigned packhi(unsigned hi, unsigned lo) {
  return __builtin_amdgcn_perm(hi, lo, 0x07060302u);
}
// residual after bf16 truncation (exact in f32)
__device__ __forceinline__ float resid(float x) {
  return x - __uint_as_float(__float_as_uint(x) & 0xffff0000u);
}
__device__ __forceinline__ f32x16 mfma_bf16(bf16x8 a, bf16x8 b, f32x16 c) {
  return __builtin_amdgcn_mfma_f32_32x32x16_bf16(a, b, c, 0, 0, 0);
}

// ---- Transpose + bf16-pack of Q,K into per-channel contiguous arrays ------
// Full-line reads (tiled) and full-line writes (128B per channel per tile).
// kpack[c] (4096B): elem e hi-b16 at byte swzA(2e), lo at 2048+swzA(2e)
//   -> byte-identical to the validated corr LDS k layout.
// qpack[c] (4096B): pair d: hi dword @8d (elems 2d lo16, 2d+1 hi16), lo @8d+4
//   -> byte-identical to the validated qe layout (pads added by consumer).
__global__ __launch_bounds__(256) void pack_qk(const float* __restrict__ Qg,
                                               const float* __restrict__ Kg,
                                               unsigned char* __restrict__ kpack,
                                               unsigned char* __restrict__ qpack) {
  __shared__ float tile[32][33];
  int zz = blockIdx.z;   // 0..31: 16 batches x {Q,K}
  const float* src = (zz < 16 ? Qg : Kg) + (size_t)(zz & 15) * 1024 * 512;
  int t0 = blockIdx.y * 32, c0 = blockIdx.x * 32;
  int tx = threadIdx.x, ty = threadIdx.y;   // block (32,8)
#pragma unroll
  for (int j = 0; j < 32; j += 8)
    tile[ty + j][tx] = src[(size_t)(t0 + ty + j) * 512 + (c0 + tx)];
  __syncthreads();
  int cg = (zz & 15) * 512 + c0 + tx;       // global channel
  int e0 = 4 * ty;                          // local t base; global e = t0+e0
  float f0 = tile[e0][tx], f1 = tile[e0 + 1][tx];
  float f2 = tile[e0 + 2][tx], f3 = tile[e0 + 3][tx];
  unsigned h0 = packhi(__float_as_uint(f1), __float_as_uint(f0));
  unsigned h1 = packhi(__float_as_uint(f3), __float_as_uint(f2));
  unsigned l0 = packhi(__float_as_uint(resid(f1)), __float_as_uint(resid(f0)));
  unsigned l1 = packhi(__float_as_uint(resid(f3)), __float_as_uint(resid(f2)));
  if (zz < 16) {   // Q: interleaved {hi(d0), lo(d0), hi(d0+1), lo(d0+1)} @ 4*e
    *(uint4*)(qpack + (size_t)cg * 4096 + 4 * (t0 + e0)) = make_uint4(h0, l0, h1, l1);
  } else {         // K: swizzled hi/lo halves
    unsigned a = swzA((unsigned)(2 * (t0 + e0)));
    *(uint2*)(kpack + (size_t)cg * 4096 + a)        = make_uint2(h0, h1);
    *(uint2*)(kpack + (size_t)cg * 4096 + 2048 + a) = make_uint2(l0, l1);
  }
}

// ---- Fused: MFMA circular correlation + top-13 + softmax + aggregation ----
// One wave per channel, 4 channels per block.  Staging = wave-private
// contiguous memcpy of pre-packed data (no sync, no conversion).  Main loop
// and top-k verbatim from the validated round-4 kernel.  Then aggregation:
// w/idx are already in registers (all lanes), V is staged cooperatively
// (sibling blocks sharing V lines are co-XCD via the bijective %8 swizzle),
// per-access clamp gather from the (dead) k LDS region, block transpose
// through the (dead) qo region, full-float4 out writes.
//   D[a][v] = sum_t k[(t+32a) mod 1024] * q[(t - r'(v)) mod 1024]
//           = corr'[32a + r'(v)],   r'(v) = 2*(v&15) + (v>>4)
// tau = (1024 - tau') & 1023.
__global__ __launch_bounds__(256) void corr_fused_kernel(const unsigned char* __restrict__ qpack,
                                                         const unsigned char* __restrict__ kpack,
                                                         const float* __restrict__ Vg,
                                                         float* __restrict__ outg) {
  __shared__ __align__(16) unsigned char lds_raw[4 * CH_BYTES];  // 49664 B
  const int tid = threadIdx.x, wave = tid >> 6, lane = tid & 63;
  // XCD-bijective swizzle: blocks {4k..4k+3} (which share output/V lines)
  // land on the same XCD (dispatch round-robins bid%8 across 8 XCDs).
  const int bid = blockIdx.x;                 // grid = 2048
  const int cblk = (bid & 7) * 256 + (bid >> 3);
  const int cg0 = cblk * 4;                   // first channel of block
  const int b = cg0 >> 9, col0 = cg0 & 511;
  const int c = cg0 + wave;                   // this wave's channel
  unsigned char* myc = lds_raw + wave * CH_BYTES;

  // ---- wave-private staging of packed k,q (contiguous, coalesced) ---------
  {
    const uint4* ks = (const uint4*)(kpack + (size_t)c * 4096);
    const uint4* qs = (const uint4*)(qpack + (size_t)c * 4096);
    uint4* kd = (uint4*)myc;
    uint4* qd = (uint4*)(myc + 4096);
#pragma unroll
    for (int it = 0; it < 4; ++it) {
      kd[lane + 64 * it] = ks[lane + 64 * it];
      qd[lane + 64 * it] = qs[lane + 64 * it];
    }
    if (lane < 2) qd[256 + lane] = qs[lane];  // qe pads: pairs 512..515 = 0..3
  }

  // ---- build odd-shifted q copy (own channel, own wave) -------------------
  {
    unsigned* qe = (unsigned*)(myc + 4096);
    unsigned* qo = (unsigned*)(myc + 8256);
    uint4 r0 = *(const uint4*)(qe + 16 * lane);
    uint4 r1 = *(const uint4*)(qe + 16 * lane + 4);
    uint4 r2 = *(const uint4*)(qe + 16 * lane + 8);
    uint4 r3 = *(const uint4*)(qe + 16 * lane + 12);
    uint2 r4 = *(const uint2*)(qe + 16 * lane + 16);
    unsigned h9[9] = {r0.x, r0.z, r1.x, r1.z, r2.x, r2.z, r3.x, r3.z, r4.x};
    unsigned l9[9] = {r0.y, r0.w, r1.y, r1.w, r2.y, r2.w, r3.y, r3.w, r4.y};
    unsigned o16[16];
#pragma unroll
    for (int i = 0; i < 8; ++i) {
      o16[2 * i]     = __builtin_amdgcn_alignbyte(h9[i + 1], h9[i], 2);
      o16[2 * i + 1] = __builtin_amdgcn_alignbyte(l9[i + 1], l9[i], 2);
    }
    *(uint4*)(qo + 16 * lane)      = make_uint4(o16[0],  o16[1],  o16[2],  o16[3]);
    *(uint4*)(qo + 16 * lane + 4)  = make_uint4(o16[4],  o16[5],  o16[6],  o16[7]);
    *(uint4*)(qo + 16 * lane + 8)  = make_uint4(o16[8],  o16[9],  o16[10], o16[11]);
    *(uint4*)(qo + 16 * lane + 12) = make_uint4(o16[12], o16[13], o16[14], o16[15]);
    if (lane == 0) {  // qo wrap pad
      *(uint4*)(qo + 1024) = make_uint4(o16[0], o16[1], o16[2], o16[3]);
      *(uint4*)(qo + 1028) = make_uint4(o16[4], o16[5], o16[6], o16[7]);
    }
  }

  // ---- main GEMM loop (validated) -----------------------------------------
  const int row = lane & 31, Hh = lane >> 5;
  const int rp  = 2 * (row & 15) + (row >> 4);       // fine shift r'(col)
  unsigned e0   = (unsigned)((8 * Hh - rp) & 1023);  // first q element needed
  const int par = rp & 1;
  const unsigned char* bArr = myc + (par ? 8256 : 4096);
  unsigned boff = (((par ? (e0 - 1) : e0) >> 1) * 8u);  // byte offset of pair
  unsigned tb   = (unsigned)(64 * row + 16 * Hh);       // k byte offset (mod 2048)

  f32x16 d = {};
#pragma unroll 4
  for (int ks = 0; ks < 64; ++ks) {
    unsigned sa = swzA(tb);
    uint4 Ah = *(const uint4*)(myc + sa);          // khi b128
    uint4 Al = *(const uint4*)(myc + 2048 + sa);   // klo b128
    uint2 p0 = *(const uint2*)(bArr + boff);
    uint2 p1 = *(const uint2*)(bArr + boff + 8);
    uint2 p2 = *(const uint2*)(bArr + boff + 16);
    uint2 p3 = *(const uint2*)(bArr + boff + 24);
    bf16x8 fah = __builtin_bit_cast(bf16x8, Ah);
    bf16x8 fal = __builtin_bit_cast(bf16x8, Al);
    bf16x8 fbh = __builtin_bit_cast(bf16x8, make_uint4(p0.x, p1.x, p2.x, p3.x));
    bf16x8 fbl = __builtin_bit_cast(bf16x8, make_uint4(p0.y, p1.y, p2.y, p3.y));
    d = mfma_bf16(fah, fbh, d);   // hi*hi
    d = mfma_bf16(fal, fbh, d);   // lo(k)*hi(q)
    d = mfma_bf16(fah, fbl, d);   // hi(k)*lo(q)
    tb   = (tb + 32u) & 2047u;
    boff = (boff + 64u) & 4095u;
  }

  // ---- top-13 straight on the accumulator (tau'-space indices) ------------
  float acc[16];
#pragma unroll
  for (int i = 0; i < 16; ++i) acc[i] = d[i];
  const int ibase = 128 * Hh + rp;

  float topv[TOPK]; int topi[TOPK];
  for (int r = 0; r < TOPK; ++r) {
    float m = -FLT_MAX; int mi = 0x7fffffff;
#pragma unroll
    for (int j = 0; j < 16; ++j) {
      int idx = ibase + 32 * ((j & 3) + 8 * (j >> 2));
      if (acc[j] > m || (acc[j] == m && idx < mi)) { m = acc[j]; mi = idx; }
    }
#pragma unroll
    for (int offx = 32; offx >= 1; offx >>= 1) {
      float om = __shfl_xor(m, offx);
      int   oi = __shfl_xor(mi, offx);
      if (om > m || (om == m && oi < mi)) { m = om; mi = oi; }
    }
    topv[r] = m; topi[r] = mi;
#pragma unroll
    for (int j = 0; j < 16; ++j)        // static-indexed knockout
      acc[j] = (ibase + 32 * ((j & 3) + 8 * (j >> 2)) == mi) ? -FLT_MAX : acc[j];
  }
  // softmax weights + delay indices, in registers of ALL lanes
  float mx = topv[0];
  float w[TOPK]; float wsum = 0.f;
#pragma unroll
  for (int r = 0; r < TOPK; ++r) { w[r] = __expf(topv[r] - mx); wsum += w[r]; }
  float inv = 1.0f / wsum;
  int di[TOPK];
#pragma unroll
  for (int r = 0; r < TOPK; ++r) { w[r] *= inv; di[r] = (1024 - topi[r]) & 1023; }

  // ---- cooperative V staging into the (dead) k regions --------------------
  __syncthreads();   // everyone done reading their k/q LDS
  {
    const float* Vb = Vg + ((size_t)b * 1024) * 512 + col0;
#pragma unroll
    for (int j = 0; j < 4; ++j) {
      int t = tid + 256 * j;
      float4 vv = *(const float4*)(Vb + (size_t)t * 512);
      ((float*)(lds_raw + 0 * CH_BYTES))[t] = vv.x;
      ((float*)(lds_raw + 1 * CH_BYTES))[t] = vv.y;
      ((float*)(lds_raw + 2 * CH_BYTES))[t] = vv.z;
      ((float*)(lds_raw + 3 * CH_BYTES))[t] = vv.w;
    }
  }
  __syncthreads();

  // ---- aggregation: out[t] = sum_i w_i * v[min(di_i + t, 1023)] -----------
  {
    const float* vls = (const float*)myc;
    float* obuf = (float*)(myc + 8256);      // dead qo region
#pragma unroll 4
    for (int j = 0; j < 16; ++j) {
      int t = lane + 64 * j;
      float a = 0.f;
#pragma unroll
      for (int i = 0; i < TOPK; ++i) {
        int src = di[i] + t; src = src < 1023 ? src : 1023;
        a += w[i] * vls[src];
      }
      obuf[t] = a;
    }
  }
  __syncthreads();

  // ---- transpose-write: full float4 rows out[b][t][col0..col0+3] ----------
  {
    float* o = outg + ((size_t)b * 1024) * 512 + col0;
#pragma unroll
    for (int jj = 0; jj < 4; ++jj) {
      int t = tid + 256 * jj;
      float4 ov;
      ov.x = ((const float*)(lds_raw + 0 * CH_BYTES + 8256))[t];
      ov.y = ((const float*)(lds_raw + 1 * CH_BYTES + 8256))[t];
      ov.z = ((const float*)(lds_raw + 2 * CH_BYTES + 8256))[t];
      ov.w = ((const float*)(lds_raw + 3 * CH_BYTES + 8256))[t];
      *(float4*)(o + (size_t)t * 512) = ov;
    }
  }
}

extern "C" void kernel_launch(void* const* d_in, const int* in_sizes, int n_in,
                              void* d_out, int out_size, void* d_ws, size_t ws_size,
                              hipStream_t stream) {
  const float* Q = (const float*)d_in[0];
  const float* K = (const float*)d_in[1];
  const float* V = (const float*)d_in[2];
  float* out = (float*)d_out;
  // ws layout (bytes): kpack[8192*4096] | qpack[8192*4096]  (= 64 MiB <= ws)
  unsigned char* kpack = (unsigned char*)d_ws;
  unsigned char* qpack = kpack + (size_t)NCH * 4096;

  dim3 tb(32, 8);
  pack_qk<<<dim3(16, 32, 32), tb, 0, stream>>>(Q, K, kpack, qpack);
  corr_fused_kernel<<<NCH / 4, 256, 0, stream>>>(qpack, kpack, V, out);
}

// Round 6
// 245.080 us; speedup vs baseline: 1.1756x; 1.0072x over previous
//
#include <hip/hip_runtime.h>
#include <float.h>

#define LSEQ 1024
#define NCH  8192   // B*H*d = 16*8*64
#define TOPK 13     // int(2*ln(1024))

typedef short bf16x8 __attribute__((ext_vector_type(8)));   // 8 bf16 = 4 VGPRs (MFMA A/B frag)
typedef float f32x16 __attribute__((ext_vector_type(16)));  // MFMA C/D frag

// Per-channel LDS layout (bytes) in the fused kernel:
//   khi [0,2048)  klo [2048,4096)     (swizzled, circular mod-2048B) -- later reused as v row
//   qe  [4096, 8256)  interleaved: byte 8d = hi-pair d, 8d+4 = lo-pair d; pads pairs 512..515
//   qo  [8256, 12416) odd-shifted copy -- later reused as obuf
#define CH_BYTES 12416

// A-read swizzle: b4 ^= b7, b5 ^= b8 ^ b6.  Spreads the 64 lanes' b128 reads
// (addr = 64*row + 32*ks + 16*H mod 2048) over all 8 bank positions.
// Only bits 4,5 change -> swzA(a+x) = swzA(a)+x within a 16B block, and a
// 16B-aligned block maps to a 16B-aligned block inside the same 64B line.
__device__ __forceinline__ unsigned swzA(unsigned a) {
  return a ^ ((a >> 3) & 48u) ^ ((a >> 1) & 32u);
}
// pack bf16(hi16) of two f32 into one word: low half = lo-arg, high half = hi-arg
__device__ __forceinline__ unsigned packhi(unsigned hi, unsigned lo) {
  return __builtin_amdgcn_perm(hi, lo, 0x07060302u);
}
// residual after bf16 truncation (exact in f32)
__device__ __forceinline__ float resid(float x) {
  return x - __uint_as_float(__float_as_uint(x) & 0xffff0000u);
}
__device__ __forceinline__ f32x16 mfma_bf16(bf16x8 a, bf16x8 b, f32x16 c) {
  return __builtin_amdgcn_mfma_f32_32x32x16_bf16(a, b, c, 0, 0, 0);
}

// ---- Transpose + bf16-pack of Q,K into per-channel contiguous arrays ------
// Read phase: 32x32 tile, full-line reads.  Write phase (fixed in round 6):
// thread -> (channel = tid>>3, 16B piece), so 8 consecutive lanes write 128
// CONTIGUOUS bytes of one channel: every 64B line is fully covered within a
// single wave (round-5 version scattered 16B stores at 4096B stride -> the
// kernel was store-transaction-bound at ~115us).
// kpack[c] (4096B): elem e hi-b16 at byte swzA(2e), lo at 2048+swzA(2e)
// qpack[c] (4096B): pair d: hi dword @8d (elems 2d,2d+1), lo dword @8d+4
//   -> byte-identical to the validated corr LDS layouts.
__global__ __launch_bounds__(256) void pack_qk(const float* __restrict__ Qg,
                                               const float* __restrict__ Kg,
                                               unsigned char* __restrict__ kpack,
                                               unsigned char* __restrict__ qpack) {
  __shared__ float tile[32][33];
  const int tid = threadIdx.x;
  int zz = blockIdx.z;   // 0..31: 16 batches x {Q,K}
  const float* src = (zz < 16 ? Qg : Kg) + (size_t)(zz & 15) * 1024 * 512;
  int t0 = blockIdx.y * 32, c0 = blockIdx.x * 32;
  int tx = tid & 31, ty = tid >> 5;
#pragma unroll
  for (int j = 0; j < 32; j += 8)
    tile[ty + j][tx] = src[(size_t)(t0 + ty + j) * 512 + (c0 + tx)];
  __syncthreads();

  const int chl = tid >> 3;                      // 0..31 local channel
  const size_t cbase = (size_t)((zz & 15) * 512 + c0 + chl) * 4096;
  if (zz < 16) {
    // Q: piece = tid&7 covers local elems 4p..4p+3 -> uint4 {h0,l0,h1,l1}
    const int p = tid & 7;
    float f0 = tile[4 * p + 0][chl], f1 = tile[4 * p + 1][chl];
    float f2 = tile[4 * p + 2][chl], f3 = tile[4 * p + 3][chl];
    unsigned h0 = packhi(__float_as_uint(f1), __float_as_uint(f0));
    unsigned h1 = packhi(__float_as_uint(f3), __float_as_uint(f2));
    unsigned l0 = packhi(__float_as_uint(resid(f1)), __float_as_uint(resid(f0)));
    unsigned l1 = packhi(__float_as_uint(resid(f3)), __float_as_uint(resid(f2)));
    *(uint4*)(qpack + cbase + 4u * (unsigned)(t0 + 4 * p)) = make_uint4(h0, l0, h1, l1);
  } else {
    // K: half = hi/lo, piece covers local elems 8p..8p+7 -> uint4 of 4 dwords
    const int half = (tid >> 2) & 1, p = tid & 3;
    float f[8];
#pragma unroll
    for (int i = 0; i < 8; ++i) f[i] = tile[8 * p + i][chl];
    unsigned wds[4];
    if (half == 0) {
#pragma unroll
      for (int d = 0; d < 4; ++d)
        wds[d] = packhi(__float_as_uint(f[2 * d + 1]), __float_as_uint(f[2 * d]));
    } else {
#pragma unroll
      for (int d = 0; d < 4; ++d)
        wds[d] = packhi(__float_as_uint(resid(f[2 * d + 1])),
                        __float_as_uint(resid(f[2 * d])));
    }
    unsigned a = swzA((unsigned)(2 * t0 + 16 * p));   // 16B-aligned, line-local
    *(uint4*)(kpack + cbase + 2048u * (unsigned)half + a) =
        make_uint4(wds[0], wds[1], wds[2], wds[3]);
  }
}

// ---- Fused: MFMA circular correlation + top-13 + softmax + aggregation ----
// (unchanged from round 5 -- validated)
//   D[a][v] = sum_t k[(t+32a) mod 1024] * q[(t - r'(v)) mod 1024]
//           = corr'[32a + r'(v)],   r'(v) = 2*(v&15) + (v>>4)
// tau = (1024 - tau') & 1023.
__global__ __launch_bounds__(256) void corr_fused_kernel(const unsigned char* __restrict__ qpack,
                                                         const unsigned char* __restrict__ kpack,
                                                         const float* __restrict__ Vg,
                                                         float* __restrict__ outg) {
  __shared__ __align__(16) unsigned char lds_raw[4 * CH_BYTES];  // 49664 B
  const int tid = threadIdx.x, wave = tid >> 6, lane = tid & 63;
  // XCD-bijective swizzle: blocks {4k..4k+3} (which share output/V lines)
  // land on the same XCD (dispatch round-robins bid%8 across 8 XCDs).
  const int bid = blockIdx.x;                 // grid = 2048
  const int cblk = (bid & 7) * 256 + (bid >> 3);
  const int cg0 = cblk * 4;                   // first channel of block
  const int b = cg0 >> 9, col0 = cg0 & 511;
  const int c = cg0 + wave;                   // this wave's channel
  unsigned char* myc = lds_raw + wave * CH_BYTES;

  // ---- wave-private staging of packed k,q (contiguous, coalesced) ---------
  {
    const uint4* ks = (const uint4*)(kpack + (size_t)c * 4096);
    const uint4* qs = (const uint4*)(qpack + (size_t)c * 4096);
    uint4* kd = (uint4*)myc;
    uint4* qd = (uint4*)(myc + 4096);
#pragma unroll
    for (int it = 0; it < 4; ++it) {
      kd[lane + 64 * it] = ks[lane + 64 * it];
      qd[lane + 64 * it] = qs[lane + 64 * it];
    }
    if (lane < 2) qd[256 + lane] = qs[lane];  // qe pads: pairs 512..515 = 0..3
  }

  // ---- build odd-shifted q copy (own channel, own wave) -------------------
  {
    unsigned* qe = (unsigned*)(myc + 4096);
    unsigned* qo = (unsigned*)(myc + 8256);
    uint4 r0 = *(const uint4*)(qe + 16 * lane);
    uint4 r1 = *(const uint4*)(qe + 16 * lane + 4);
    uint4 r2 = *(const uint4*)(qe + 16 * lane + 8);
    uint4 r3 = *(const uint4*)(qe + 16 * lane + 12);
    uint2 r4 = *(const uint2*)(qe + 16 * lane + 16);
    unsigned h9[9] = {r0.x, r0.z, r1.x, r1.z, r2.x, r2.z, r3.x, r3.z, r4.x};
    unsigned l9[9] = {r0.y, r0.w, r1.y, r1.w, r2.y, r2.w, r3.y, r3.w, r4.y};
    unsigned o16[16];
#pragma unroll
    for (int i = 0; i < 8; ++i) {
      o16[2 * i]     = __builtin_amdgcn_alignbyte(h9[i + 1], h9[i], 2);
      o16[2 * i + 1] = __builtin_amdgcn_alignbyte(l9[i + 1], l9[i], 2);
    }
    *(uint4*)(qo + 16 * lane)      = make_uint4(o16[0],  o16[1],  o16[2],  o16[3]);
    *(uint4*)(qo + 16 * lane + 4)  = make_uint4(o16[4],  o16[5],  o16[6],  o16[7]);
    *(uint4*)(qo + 16 * lane + 8)  = make_uint4(o16[8],  o16[9],  o16[10], o16[11]);
    *(uint4*)(qo + 16 * lane + 12) = make_uint4(o16[12], o16[13], o16[14], o16[15]);
    if (lane == 0) {  // qo wrap pad
      *(uint4*)(qo + 1024) = make_uint4(o16[0], o16[1], o16[2], o16[3]);
      *(uint4*)(qo + 1028) = make_uint4(o16[4], o16[5], o16[6], o16[7]);
    }
  }

  // ---- main GEMM loop (validated) -----------------------------------------
  const int row = lane & 31, Hh = lane >> 5;
  const int rp  = 2 * (row & 15) + (row >> 4);       // fine shift r'(col)
  unsigned e0   = (unsigned)((8 * Hh - rp) & 1023);  // first q element needed
  const int par = rp & 1;
  const unsigned char* bArr = myc + (par ? 8256 : 4096);
  unsigned boff = (((par ? (e0 - 1) : e0) >> 1) * 8u);  // byte offset of pair
  unsigned tb   = (unsigned)(64 * row + 16 * Hh);       // k byte offset (mod 2048)

  f32x16 d = {};
#pragma unroll 4
  for (int ks = 0; ks < 64; ++ks) {
    unsigned sa = swzA(tb);
    uint4 Ah = *(const uint4*)(myc + sa);          // khi b128
    uint4 Al = *(const uint4*)(myc + 2048 + sa);   // klo b128
    uint2 p0 = *(const uint2*)(bArr + boff);
    uint2 p1 = *(const uint2*)(bArr + boff + 8);
    uint2 p2 = *(const uint2*)(bArr + boff + 16);
    uint2 p3 = *(const uint2*)(bArr + boff + 24);
    bf16x8 fah = __builtin_bit_cast(bf16x8, Ah);
    bf16x8 fal = __builtin_bit_cast(bf16x8, Al);
    bf16x8 fbh = __builtin_bit_cast(bf16x8, make_uint4(p0.x, p1.x, p2.x, p3.x));
    bf16x8 fbl = __builtin_bit_cast(bf16x8, make_uint4(p0.y, p1.y, p2.y, p3.y));
    d = mfma_bf16(fah, fbh, d);   // hi*hi
    d = mfma_bf16(fal, fbh, d);   // lo(k)*hi(q)
    d = mfma_bf16(fah, fbl, d);   // hi(k)*lo(q)
    tb   = (tb + 32u) & 2047u;
    boff = (boff + 64u) & 4095u;
  }

  // ---- top-13 straight on the accumulator (tau'-space indices) ------------
  float acc[16];
#pragma unroll
  for (int i = 0; i < 16; ++i) acc[i] = d[i];
  const int ibase = 128 * Hh + rp;

  float topv[TOPK]; int topi[TOPK];
  for (int r = 0; r < TOPK; ++r) {
    float m = -FLT_MAX; int mi = 0x7fffffff;
#pragma unroll
    for (int j = 0; j < 16; ++j) {
      int idx = ibase + 32 * ((j & 3) + 8 * (j >> 2));
      if (acc[j] > m || (acc[j] == m && idx < mi)) { m = acc[j]; mi = idx; }
    }
#pragma unroll
    for (int offx = 32; offx >= 1; offx >>= 1) {
      float om = __shfl_xor(m, offx);
      int   oi = __shfl_xor(mi, offx);
      if (om > m || (om == m && oi < mi)) { m = om; mi = oi; }
    }
    topv[r] = m; topi[r] = mi;
#pragma unroll
    for (int j = 0; j < 16; ++j)        // static-indexed knockout
      acc[j] = (ibase + 32 * ((j & 3) + 8 * (j >> 2)) == mi) ? -FLT_MAX : acc[j];
  }
  // softmax weights + delay indices, in registers of ALL lanes
  float mx = topv[0];
  float w[TOPK]; float wsum = 0.f;
#pragma unroll
  for (int r = 0; r < TOPK; ++r) { w[r] = __expf(topv[r] - mx); wsum += w[r]; }
  float inv = 1.0f / wsum;
  int di[TOPK];
#pragma unroll
  for (int r = 0; r < TOPK; ++r) { w[r] *= inv; di[r] = (1024 - topi[r]) & 1023; }

  // ---- cooperative V staging into the (dead) k regions --------------------
  __syncthreads();   // everyone done reading their k/q LDS
  {
    const float* Vb = Vg + ((size_t)b * 1024) * 512 + col0;
#pragma unroll
    for (int j = 0; j < 4; ++j) {
      int t = tid + 256 * j;
      float4 vv = *(const float4*)(Vb + (size_t)t * 512);
      ((float*)(lds_raw + 0 * CH_BYTES))[t] = vv.x;
      ((float*)(lds_raw + 1 * CH_BYTES))[t] = vv.y;
      ((float*)(lds_raw + 2 * CH_BYTES))[t] = vv.z;
      ((float*)(lds_raw + 3 * CH_BYTES))[t] = vv.w;
    }
  }
  __syncthreads();

  // ---- aggregation: out[t] = sum_i w_i * v[min(di_i + t, 1023)] -----------
  {
    const float* vls = (const float*)myc;
    float* obuf = (float*)(myc + 8256);      // dead qo region
#pragma unroll 4
    for (int j = 0; j < 16; ++j) {
      int t = lane + 64 * j;
      float a = 0.f;
#pragma unroll
      for (int i = 0; i < TOPK; ++i) {
        int src = di[i] + t; src = src < 1023 ? src : 1023;
        a += w[i] * vls[src];
      }
      obuf[t] = a;
    }
  }
  __syncthreads();

  // ---- transpose-write: full float4 rows out[b][t][col0..col0+3] ----------
  {
    float* o = outg + ((size_t)b * 1024) * 512 + col0;
#pragma unroll
    for (int jj = 0; jj < 4; ++jj) {
      int t = tid + 256 * jj;
      float4 ov;
      ov.x = ((const float*)(lds_raw + 0 * CH_BYTES + 8256))[t];
      ov.y = ((const float*)(lds_raw + 1 * CH_BYTES + 8256))[t];
      ov.z = ((const float*)(lds_raw + 2 * CH_BYTES + 8256))[t];
      ov.w = ((const float*)(lds_raw + 3 * CH_BYTES + 8256))[t];
      *(float4*)(o + (size_t)t * 512) = ov;
    }
  }
}

extern "C" void kernel_launch(void* const* d_in, const int* in_sizes, int n_in,
                              void* d_out, int out_size, void* d_ws, size_t ws_size,
                              hipStream_t stream) {
  const float* Q = (const float*)d_in[0];
  const float* K = (const float*)d_in[1];
  const float* V = (const float*)d_in[2];
  float* out = (float*)d_out;
  // ws layout (bytes): kpack[8192*4096] | qpack[8192*4096]  (= 64 MiB <= ws)
  unsigned char* kpack = (unsigned char*)d_ws;
  unsigned char* qpack = kpack + (size_t)NCH * 4096;

  pack_qk<<<dim3(16, 32, 32), 256, 0, stream>>>(Q, K, kpack, qpack);
  corr_fused_kernel<<<NCH / 4, 256, 0, stream>>>(qpack, kpack, V, out);
}

// Round 7
// 226.561 us; speedup vs baseline: 1.2717x; 1.0817x over previous
//
#include <hip/hip_runtime.h>
#include <float.h>

#define LSEQ 1024
#define NCH  8192   // B*H*d = 16*8*64
#define TOPK 13     // int(2*ln(1024))

typedef short bf16x8 __attribute__((ext_vector_type(8)));   // 8 bf16 = 4 VGPRs (MFMA A/B frag)
typedef float f32x16 __attribute__((ext_vector_type(16)));  // MFMA C/D frag

// Per-channel LDS layout (bytes):
//   khi [0,2048)  klo [2048,4096)     (swizzled, circular mod-2048B) -- later reused as v row
//   qe  [4096, 8256)  interleaved: byte 8d = hi-pair d, 8d+4 = lo-pair d; pads pairs 512..515
//   qo  [8256, 12416) odd-shifted copy -- later reused as obuf
#define CH_BYTES 12416

// A-read swizzle: b4 ^= b7, b5 ^= b8 ^ b6.  Spreads the 64 lanes' b128 reads
// (addr = 64*row + 32*ks + 16*H mod 2048) over all 8 bank positions.
// Only bits 4,5 change -> swzA(a+x) = swzA(a)+x for x<16.
__device__ __forceinline__ unsigned swzA(unsigned a) {
  return a ^ ((a >> 3) & 48u) ^ ((a >> 1) & 32u);
}
// residual after bf16 truncation (exact in f32)
__device__ __forceinline__ float resid(float x) {
  return x - __uint_as_float(__float_as_uint(x) & 0xffff0000u);
}
__device__ __forceinline__ f32x16 mfma_bf16(bf16x8 a, bf16x8 b, f32x16 c) {
  return __builtin_amdgcn_mfma_f32_32x32x16_bf16(a, b, c, 0, 0, 0);
}

// ---- Single fused kernel: stage Q,K from raw layout -> MFMA circular ------
// correlation -> top-13 -> softmax -> time-delay aggregation -> output.
// One wave per channel, 4 channels per block.  The bijective XCD swizzle
// puts the 4 sibling blocks that share every Q/K/V/out 64B line on the SAME
// XCD (dispatch round-robins bid%8 across the 8 XCDs), so the 16B/line
// per-block staging reads are L2-shared, not re-fetched (round-4's 262MB
// over-fetch -> ~compulsory).  Staging layout is byte-identical to the
// validated rounds 4-6.  Main loop:
//   D[a][v] = sum_t k[(t+32a) mod 1024] * q[(t - r'(v)) mod 1024]
//           = corr'[32a + r'(v)],   r'(v) = 2*(v&15) + (v>>4)
// tau = (1024 - tau') & 1023.
__global__ __launch_bounds__(256) void corr_mega_kernel(const float* __restrict__ Qg,
                                                        const float* __restrict__ Kg,
                                                        const float* __restrict__ Vg,
                                                        float* __restrict__ outg) {
  __shared__ __align__(16) unsigned char lds_raw[4 * CH_BYTES];  // 49664 B
  const int tid = threadIdx.x, wave = tid >> 6, lane = tid & 63;
  const int bid = blockIdx.x;                 // grid = 2048
  const int cblk = (bid & 7) * 256 + (bid >> 3);
  const int cg0 = cblk * 4;                   // first channel of block
  const int b = cg0 >> 9, col0 = cg0 & 511;
  const int c = cg0 + wave;                   // this wave's channel (unused below but kept for clarity)
  (void)c;
  unsigned char* myc = lds_raw + wave * CH_BYTES;

  // ---- block-cooperative staging from raw [B,1024,512] --------------------
  // Each thread's float4 covers exactly the block's 4 channels at row t.
  {
    const float* Qb = Qg + ((size_t)b * 1024) * 512 + col0;
    const float* Kb = Kg + ((size_t)b * 1024) * 512 + col0;
#pragma unroll
    for (int j = 0; j < 4; ++j) {
      int t = tid + 256 * j;
      float4 kv = *(const float4*)(Kb + (size_t)t * 512);
      float4 qv = *(const float4*)(Qb + (size_t)t * 512);
      unsigned ka0 = swzA(4u * (unsigned)(t >> 1) + 2u * (unsigned)(t & 1)); // = swzA(2t)
      unsigned qa0 = 8u * (unsigned)(t >> 1) + 2u * (unsigned)(t & 1);
      float karr[4] = {kv.x, kv.y, kv.z, kv.w};
      float qarr[4] = {qv.x, qv.y, qv.z, qv.w};
#pragma unroll
      for (int cc = 0; cc < 4; ++cc) {
        unsigned char* ck = lds_raw + cc * CH_BYTES;
        unsigned khiv = __float_as_uint(karr[cc]) >> 16;
        unsigned klov = __float_as_uint(resid(karr[cc])) >> 16;
        *(unsigned short*)(ck + ka0)        = (unsigned short)khiv;
        *(unsigned short*)(ck + 2048 + ka0) = (unsigned short)klov;
        unsigned qhiv = __float_as_uint(qarr[cc]) >> 16;
        unsigned qlov = __float_as_uint(resid(qarr[cc])) >> 16;
        *(unsigned short*)(ck + 4096 + qa0)     = (unsigned short)qhiv;
        *(unsigned short*)(ck + 4096 + qa0 + 4) = (unsigned short)qlov;
        if (t < 8) {  // qe wrap pad: elems 1024..1031 = elems 0..7
          *(unsigned short*)(ck + 8192 + qa0)     = (unsigned short)qhiv;
          *(unsigned short*)(ck + 8192 + qa0 + 4) = (unsigned short)qlov;
        }
      }
    }
  }
  __syncthreads();

  // ---- build odd-shifted q copy (own channel, own wave) -------------------
  {
    unsigned* qe = (unsigned*)(myc + 4096);
    unsigned* qo = (unsigned*)(myc + 8256);
    uint4 r0 = *(const uint4*)(qe + 16 * lane);
    uint4 r1 = *(const uint4*)(qe + 16 * lane + 4);
    uint4 r2 = *(const uint4*)(qe + 16 * lane + 8);
    uint4 r3 = *(const uint4*)(qe + 16 * lane + 12);
    uint2 r4 = *(const uint2*)(qe + 16 * lane + 16);
    unsigned h9[9] = {r0.x, r0.z, r1.x, r1.z, r2.x, r2.z, r3.x, r3.z, r4.x};
    unsigned l9[9] = {r0.y, r0.w, r1.y, r1.w, r2.y, r2.w, r3.y, r3.w, r4.y};
    unsigned o16[16];
#pragma unroll
    for (int i = 0; i < 8; ++i) {
      o16[2 * i]     = __builtin_amdgcn_alignbyte(h9[i + 1], h9[i], 2);
      o16[2 * i + 1] = __builtin_amdgcn_alignbyte(l9[i + 1], l9[i], 2);
    }
    *(uint4*)(qo + 16 * lane)      = make_uint4(o16[0],  o16[1],  o16[2],  o16[3]);
    *(uint4*)(qo + 16 * lane + 4)  = make_uint4(o16[4],  o16[5],  o16[6],  o16[7]);
    *(uint4*)(qo + 16 * lane + 8)  = make_uint4(o16[8],  o16[9],  o16[10], o16[11]);
    *(uint4*)(qo + 16 * lane + 12) = make_uint4(o16[12], o16[13], o16[14], o16[15]);
    if (lane == 0) {  // qo wrap pad
      *(uint4*)(qo + 1024) = make_uint4(o16[0], o16[1], o16[2], o16[3]);
      *(uint4*)(qo + 1028) = make_uint4(o16[4], o16[5], o16[6], o16[7]);
    }
  }

  // ---- main GEMM loop (validated) -----------------------------------------
  const int row = lane & 31, Hh = lane >> 5;
  const int rp  = 2 * (row & 15) + (row >> 4);       // fine shift r'(col)
  unsigned e0   = (unsigned)((8 * Hh - rp) & 1023);  // first q element needed
  const int par = rp & 1;
  const unsigned char* bArr = myc + (par ? 8256 : 4096);
  unsigned boff = (((par ? (e0 - 1) : e0) >> 1) * 8u);  // byte offset of pair
  unsigned tb   = (unsigned)(64 * row + 16 * Hh);       // k byte offset (mod 2048)

  f32x16 d = {};
#pragma unroll 4
  for (int ks = 0; ks < 64; ++ks) {
    unsigned sa = swzA(tb);
    uint4 Ah = *(const uint4*)(myc + sa);          // khi b128
    uint4 Al = *(const uint4*)(myc + 2048 + sa);   // klo b128
    uint2 p0 = *(const uint2*)(bArr + boff);
    uint2 p1 = *(const uint2*)(bArr + boff + 8);
    uint2 p2 = *(const uint2*)(bArr + boff + 16);
    uint2 p3 = *(const uint2*)(bArr + boff + 24);
    bf16x8 fah = __builtin_bit_cast(bf16x8, Ah);
    bf16x8 fal = __builtin_bit_cast(bf16x8, Al);
    bf16x8 fbh = __builtin_bit_cast(bf16x8, make_uint4(p0.x, p1.x, p2.x, p3.x));
    bf16x8 fbl = __builtin_bit_cast(bf16x8, make_uint4(p0.y, p1.y, p2.y, p3.y));
    d = mfma_bf16(fah, fbh, d);   // hi*hi
    d = mfma_bf16(fal, fbh, d);   // lo(k)*hi(q)
    d = mfma_bf16(fah, fbl, d);   // hi(k)*lo(q)
    tb   = (tb + 32u) & 2047u;
    boff = (boff + 64u) & 4095u;
  }

  // ---- top-13 straight on the accumulator (tau'-space indices) ------------
  float acc[16];
#pragma unroll
  for (int i = 0; i < 16; ++i) acc[i] = d[i];
  const int ibase = 128 * Hh + rp;

  float topv[TOPK]; int topi[TOPK];
  for (int r = 0; r < TOPK; ++r) {
    float m = -FLT_MAX; int mi = 0x7fffffff;
#pragma unroll
    for (int j = 0; j < 16; ++j) {
      int idx = ibase + 32 * ((j & 3) + 8 * (j >> 2));
      if (acc[j] > m || (acc[j] == m && idx < mi)) { m = acc[j]; mi = idx; }
    }
#pragma unroll
    for (int offx = 32; offx >= 1; offx >>= 1) {
      float om = __shfl_xor(m, offx);
      int   oi = __shfl_xor(mi, offx);
      if (om > m || (om == m && oi < mi)) { m = om; mi = oi; }
    }
    topv[r] = m; topi[r] = mi;
#pragma unroll
    for (int j = 0; j < 16; ++j)        // static-indexed knockout
      acc[j] = (ibase + 32 * ((j & 3) + 8 * (j >> 2)) == mi) ? -FLT_MAX : acc[j];
  }
  // softmax weights + delay indices, in registers of ALL lanes
  float mx = topv[0];
  float w[TOPK]; float wsum = 0.f;
#pragma unroll
  for (int r = 0; r < TOPK; ++r) { w[r] = __expf(topv[r] - mx); wsum += w[r]; }
  float inv = 1.0f / wsum;
  int di[TOPK];
#pragma unroll
  for (int r = 0; r < TOPK; ++r) { w[r] *= inv; di[r] = (1024 - topi[r]) & 1023; }

  // ---- cooperative V staging into the (dead) k regions --------------------
  __syncthreads();   // everyone done reading their k/q LDS
  {
    const float* Vb = Vg + ((size_t)b * 1024) * 512 + col0;
#pragma unroll
    for (int j = 0; j < 4; ++j) {
      int t = tid + 256 * j;
      float4 vv = *(const float4*)(Vb + (size_t)t * 512);
      ((float*)(lds_raw + 0 * CH_BYTES))[t] = vv.x;
      ((float*)(lds_raw + 1 * CH_BYTES))[t] = vv.y;
      ((float*)(lds_raw + 2 * CH_BYTES))[t] = vv.z;
      ((float*)(lds_raw + 3 * CH_BYTES))[t] = vv.w;
    }
  }
  __syncthreads();

  // ---- aggregation: out[t] = sum_i w_i * v[min(di_i + t, 1023)] -----------
  {
    const float* vls = (const float*)myc;
    float* obuf = (float*)(myc + 8256);      // dead qo region
#pragma unroll 4
    for (int j = 0; j < 16; ++j) {
      int t = lane + 64 * j;
      float a = 0.f;
#pragma unroll
      for (int i = 0; i < TOPK; ++i) {
        int src = di[i] + t; src = src < 1023 ? src : 1023;
        a += w[i] * vls[src];
      }
      obuf[t] = a;
    }
  }
  __syncthreads();

  // ---- transpose-write: full float4 rows out[b][t][col0..col0+3] ----------
  {
    float* o = outg + ((size_t)b * 1024) * 512 + col0;
#pragma unroll
    for (int jj = 0; jj < 4; ++jj) {
      int t = tid + 256 * jj;
      float4 ov;
      ov.x = ((const float*)(lds_raw + 0 * CH_BYTES + 8256))[t];
      ov.y = ((const float*)(lds_raw + 1 * CH_BYTES + 8256))[t];
      ov.z = ((const float*)(lds_raw + 2 * CH_BYTES + 8256))[t];
      ov.w = ((const float*)(lds_raw + 3 * CH_BYTES + 8256))[t];
      *(float4*)(o + (size_t)t * 512) = ov;
    }
  }
}

extern "C" void kernel_launch(void* const* d_in, const int* in_sizes, int n_in,
                              void* d_out, int out_size, void* d_ws, size_t ws_size,
                              hipStream_t stream) {
  const float* Q = (const float*)d_in[0];
  const float* K = (const float*)d_in[1];
  const float* V = (const float*)d_in[2];
  float* out = (float*)d_out;
  (void)d_ws; (void)ws_size;

  corr_mega_kernel<<<NCH / 4, 256, 0, stream>>>(Q, K, V, out);
}

// Round 8
// 212.830 us; speedup vs baseline: 1.3538x; 1.0645x over previous
//
#include <hip/hip_runtime.h>
#include <float.h>

#define LSEQ 1024
#define NCH  8192   // B*H*d = 16*8*64
#define TOPK 13     // int(2*ln(1024))

typedef short bf16x8 __attribute__((ext_vector_type(8)));   // 8 bf16 = 4 VGPRs (MFMA A/B frag)
typedef float f32x16 __attribute__((ext_vector_type(16)));  // MFMA C/D frag

// Per-channel LDS layout (bytes):
//   khi [0,2048)  klo [2048,4096)   (swizzled, circular mod-2048B) -- reused as v row in agg
//   qe  [4096, 8256)  interleaved: byte 8d = hi-pair d, 8d+4 = lo-pair d;
//                     pads pairs 512..515 -- reused as obuf in agg
// qo copy REMOVED (round 8): fine odd-shift now done in-loop via v_alignbyte
// with a per-lane VGPR shift (bit-identical elements).  32.3KB/block ->
// 4 blocks/CU (16 waves) vs 3 (12) -- the kernel is latency-bound with no
// saturated pipe (MfmaUtil 14 / VALU 51 / LDS ~34 / HBM 7), so TLP wins.
#define CH_BYTES 8256

// A-read swizzle: b4 ^= b7, b5 ^= b8 ^ b6.  Spreads the 64 lanes' b128 reads
// (addr = 64*row + 32*ks + 16*H mod 2048) over all 8 bank positions.
// Only bits 4,5 change -> swzA(a+x) = swzA(a)+x for x<16.
__device__ __forceinline__ unsigned swzA(unsigned a) {
  return a ^ ((a >> 3) & 48u) ^ ((a >> 1) & 32u);
}
// residual after bf16 truncation (exact in f32)
__device__ __forceinline__ float resid(float x) {
  return x - __uint_as_float(__float_as_uint(x) & 0xffff0000u);
}
__device__ __forceinline__ f32x16 mfma_bf16(bf16x8 a, bf16x8 b, f32x16 c) {
  return __builtin_amdgcn_mfma_f32_32x32x16_bf16(a, b, c, 0, 0, 0);
}

// ---- Single fused kernel: stage Q,K -> MFMA circular correlation -> top-13
// -> softmax -> time-delay aggregation -> output.  One wave per channel,
// 4 channels per block; bijective XCD swizzle keeps the 4 sibling blocks
// sharing each 64B line on one XCD.  Main loop:
//   D[a][v] = sum_t k[(t+32a) mod 1024] * q[(t - r'(v)) mod 1024]
//           = corr'[32a + r'(v)],   r'(v) = 2*(v&15) + (v>>4)
// tau = (1024 - tau') & 1023.
__global__ __launch_bounds__(256) void corr_mega_kernel(const float* __restrict__ Qg,
                                                        const float* __restrict__ Kg,
                                                        const float* __restrict__ Vg,
                                                        float* __restrict__ outg) {
  __shared__ __align__(16) unsigned char lds_raw[4 * CH_BYTES];  // 33024 B
  const int tid = threadIdx.x, wave = tid >> 6, lane = tid & 63;
  const int bid = blockIdx.x;                 // grid = 2048
  const int cblk = (bid & 7) * 256 + (bid >> 3);
  const int cg0 = cblk * 4;                   // first channel of block
  const int b = cg0 >> 9, col0 = cg0 & 511;
  unsigned char* myc = lds_raw + wave * CH_BYTES;

  // ---- block-cooperative staging from raw [B,1024,512] --------------------
  // Each thread's float4 covers exactly the block's 4 channels at row t.
  {
    const float* Qb = Qg + ((size_t)b * 1024) * 512 + col0;
    const float* Kb = Kg + ((size_t)b * 1024) * 512 + col0;
#pragma unroll
    for (int j = 0; j < 4; ++j) {
      int t = tid + 256 * j;
      float4 kv = *(const float4*)(Kb + (size_t)t * 512);
      float4 qv = *(const float4*)(Qb + (size_t)t * 512);
      unsigned ka0 = swzA(4u * (unsigned)(t >> 1) + 2u * (unsigned)(t & 1)); // = swzA(2t)
      unsigned qa0 = 8u * (unsigned)(t >> 1) + 2u * (unsigned)(t & 1);
      float karr[4] = {kv.x, kv.y, kv.z, kv.w};
      float qarr[4] = {qv.x, qv.y, qv.z, qv.w};
#pragma unroll
      for (int cc = 0; cc < 4; ++cc) {
        unsigned char* ck = lds_raw + cc * CH_BYTES;
        unsigned khiv = __float_as_uint(karr[cc]) >> 16;
        unsigned klov = __float_as_uint(resid(karr[cc])) >> 16;
        *(unsigned short*)(ck + ka0)        = (unsigned short)khiv;
        *(unsigned short*)(ck + 2048 + ka0) = (unsigned short)klov;
        unsigned qhiv = __float_as_uint(qarr[cc]) >> 16;
        unsigned qlov = __float_as_uint(resid(qarr[cc])) >> 16;
        *(unsigned short*)(ck + 4096 + qa0)     = (unsigned short)qhiv;
        *(unsigned short*)(ck + 4096 + qa0 + 4) = (unsigned short)qlov;
        if (t < 8) {  // qe wrap pad: elems 1024..1031 = elems 0..7 (pairs 512..515)
          *(unsigned short*)(ck + 8192 + qa0)     = (unsigned short)qhiv;
          *(unsigned short*)(ck + 8192 + qa0 + 4) = (unsigned short)qlov;
        }
      }
    }
  }
  __syncthreads();

  // ---- early V loads (T14): issue now, latency hides under the GEMM loop --
  float4 vreg[4];
  {
    const float* Vb = Vg + ((size_t)b * 1024) * 512 + col0;
#pragma unroll
    for (int j = 0; j < 4; ++j)
      vreg[j] = *(const float4*)(Vb + (size_t)(tid + 256 * j) * 512);
  }

  // ---- main GEMM loop -----------------------------------------------------
  const int row = lane & 31, Hh = lane >> 5;
  const int rp  = 2 * (row & 15) + (row >> 4);       // fine shift r'(col)
  unsigned e0   = (unsigned)((8 * Hh - rp) & 1023);  // first q element needed
  const unsigned sh = 2u * (e0 & 1u);                // alignbyte shift (VGPR)
  const unsigned char* qeB = myc + 4096;
  unsigned boff = (e0 >> 1) * 8u;                    // byte offset of first pair
  unsigned tb   = (unsigned)(64 * row + 16 * Hh);    // k byte offset (mod 2048)

  f32x16 d = {};
#pragma unroll 4
  for (int ks = 0; ks < 64; ++ks) {
    unsigned sa = swzA(tb);
    uint4 Ah = *(const uint4*)(myc + sa);          // khi b128
    uint4 Al = *(const uint4*)(myc + 2048 + sa);   // klo b128
    uint2 p0 = *(const uint2*)(qeB + boff);
    uint2 p1 = *(const uint2*)(qeB + boff + 8);
    uint2 p2 = *(const uint2*)(qeB + boff + 16);
    uint2 p3 = *(const uint2*)(qeB + boff + 24);
    uint2 p4 = *(const uint2*)(qeB + boff + 32);
    // fine shift in-registers: sh=0 -> identity (S1), sh=2 -> odd shift,
    // identical operand order to the validated qo-build alignbyte.
    unsigned bh0 = __builtin_amdgcn_alignbyte(p1.x, p0.x, sh);
    unsigned bh1 = __builtin_amdgcn_alignbyte(p2.x, p1.x, sh);
    unsigned bh2 = __builtin_amdgcn_alignbyte(p3.x, p2.x, sh);
    unsigned bh3 = __builtin_amdgcn_alignbyte(p4.x, p3.x, sh);
    unsigned bl0 = __builtin_amdgcn_alignbyte(p1.y, p0.y, sh);
    unsigned bl1 = __builtin_amdgcn_alignbyte(p2.y, p1.y, sh);
    unsigned bl2 = __builtin_amdgcn_alignbyte(p3.y, p2.y, sh);
    unsigned bl3 = __builtin_amdgcn_alignbyte(p4.y, p3.y, sh);
    bf16x8 fah = __builtin_bit_cast(bf16x8, Ah);
    bf16x8 fal = __builtin_bit_cast(bf16x8, Al);
    bf16x8 fbh = __builtin_bit_cast(bf16x8, make_uint4(bh0, bh1, bh2, bh3));
    bf16x8 fbl = __builtin_bit_cast(bf16x8, make_uint4(bl0, bl1, bl2, bl3));
    d = mfma_bf16(fah, fbh, d);   // hi*hi
    d = mfma_bf16(fal, fbh, d);   // lo(k)*hi(q)
    d = mfma_bf16(fah, fbl, d);   // hi(k)*lo(q)
    tb   = (tb + 32u) & 2047u;
    boff = (boff + 64u) & 4095u;
  }

  // ---- top-13 straight on the accumulator (tau'-space indices) ------------
  float acc[16];
#pragma unroll
  for (int i = 0; i < 16; ++i) acc[i] = d[i];
  const int ibase = 128 * Hh + rp;

  float topv[TOPK]; int topi[TOPK];
  for (int r = 0; r < TOPK; ++r) {
    float m = -FLT_MAX; int mi = 0x7fffffff;
#pragma unroll
    for (int j = 0; j < 16; ++j) {
      int idx = ibase + 32 * ((j & 3) + 8 * (j >> 2));
      if (acc[j] > m || (acc[j] == m && idx < mi)) { m = acc[j]; mi = idx; }
    }
#pragma unroll
    for (int offx = 32; offx >= 1; offx >>= 1) {
      float om = __shfl_xor(m, offx);
      int   oi = __shfl_xor(mi, offx);
      if (om > m || (om == m && oi < mi)) { m = om; mi = oi; }
    }
    topv[r] = m; topi[r] = mi;
#pragma unroll
    for (int j = 0; j < 16; ++j)        // static-indexed knockout
      acc[j] = (ibase + 32 * ((j & 3) + 8 * (j >> 2)) == mi) ? -FLT_MAX : acc[j];
  }
  // softmax weights + delay indices, in registers of ALL lanes
  float mx = topv[0];
  float w[TOPK]; float wsum = 0.f;
#pragma unroll
  for (int r = 0; r < TOPK; ++r) { w[r] = __expf(topv[r] - mx); wsum += w[r]; }
  float inv = 1.0f / wsum;
  int di[TOPK];
#pragma unroll
  for (int r = 0; r < TOPK; ++r) { w[r] *= inv; di[r] = (1024 - topi[r]) & 1023; }

  // ---- V -> LDS (k region is dead now); data already in registers ---------
  __syncthreads();   // everyone done reading their k/q LDS
#pragma unroll
  for (int j = 0; j < 4; ++j) {
    int t = tid + 256 * j;
    ((float*)(lds_raw + 0 * CH_BYTES))[t] = vreg[j].x;
    ((float*)(lds_raw + 1 * CH_BYTES))[t] = vreg[j].y;
    ((float*)(lds_raw + 2 * CH_BYTES))[t] = vreg[j].z;
    ((float*)(lds_raw + 3 * CH_BYTES))[t] = vreg[j].w;
  }
  __syncthreads();

  // ---- aggregation: out[t] = sum_i w_i * v[min(di_i + t, 1023)] -----------
  {
    const float* vls = (const float*)myc;    // k region = v row (4096B)
    float* obuf = (float*)(myc + 4096);      // dead qe region
#pragma unroll 4
    for (int j = 0; j < 16; ++j) {
      int t = lane + 64 * j;
      float a = 0.f;
#pragma unroll
      for (int i = 0; i < TOPK; ++i) {
        int src = di[i] + t; src = src < 1023 ? src : 1023;
        a += w[i] * vls[src];
      }
      obuf[t] = a;
    }
  }
  __syncthreads();

  // ---- transpose-write: full float4 rows out[b][t][col0..col0+3] ----------
  {
    float* o = outg + ((size_t)b * 1024) * 512 + col0;
#pragma unroll
    for (int jj = 0; jj < 4; ++jj) {
      int t = tid + 256 * jj;
      float4 ov;
      ov.x = ((const float*)(lds_raw + 0 * CH_BYTES + 4096))[t];
      ov.y = ((const float*)(lds_raw + 1 * CH_BYTES + 4096))[t];
      ov.z = ((const float*)(lds_raw + 2 * CH_BYTES + 4096))[t];
      ov.w = ((const float*)(lds_raw + 3 * CH_BYTES + 4096))[t];
      *(float4*)(o + (size_t)t * 512) = ov;
    }
  }
}

extern "C" void kernel_launch(void* const* d_in, const int* in_sizes, int n_in,
                              void* d_out, int out_size, void* d_ws, size_t ws_size,
                              hipStream_t stream) {
  const float* Q = (const float*)d_in[0];
  const float* K = (const float*)d_in[1];
  const float* V = (const float*)d_in[2];
  float* out = (float*)d_out;
  (void)d_ws; (void)ws_size;

  corr_mega_kernel<<<NCH / 4, 256, 0, stream>>>(Q, K, V, out);
}